// Round 3
// baseline (1832.526 us; speedup 1.0000x reference)
//
#include <hip/hip_runtime.h>
#include <stddef.h>
#include <stdint.h>

// VQ argmin + gather, MI355X.
//   x:         (8, 2048, 1024) fp32 -> 16384 query rows, head h uses cols [h*128,(h+1)*128)
//   codebooks: (8, 2048, 128)  fp32
//   out[q, h*128+d] = codebooks[h, argmin_m ||q-c||^2, d]
//
// Round 3: single-pass fp16 MFMA (was 3-pass split-bf16).
//   score = 0.5*||c||^2(fp32 exact) - qc(fp16 MFMA).  dot err sigma ~0.005,
//   min-gap mean ~5 -> top-2 tracking + exact fp32 rescore of gap<TAU=0.12
//   (~2% of queries). Single pre-swizzled fp16 code image (4 MiB, per-XCD-L2
//   resident); LDS 2x16KB double buffer -> 4 blocks/CU.

#define NHEAD  8
#define NCODE  2048
#define DDIM   128
#define NQTOT  16384
#define BQ     128            // queries per main block (4 waves x 32)
#define CCH    64             // codes per chunk
#define NCHUNK (NCODE / CCH)  // 32
#define CHB    (CCH * DDIM * 2) // 16384 B per chunk image
#define TAU    0.12f
#define WS_NEED (4u*1024u*1024u + 64u*1024u)

typedef __attribute__((ext_vector_type(8))) _Float16 half8;
typedef __attribute__((ext_vector_type(4))) float f32x4;

// ---------------- kernel 1: fp16 pre-swizzled codebook image + norms --------
// img layout: per (head,chunk) a 16 KiB block; within block:
//   row = code within chunk (0..63), 16 slots of 16B (8 fp16) per row
//   slot s holds elements of source slot (s ^ (row&7))
// reader at byte addr row*256 + ((kslot ^ (row&7))*16) sees k-elements kslot*8..+7.
__global__ __launch_bounds__(256) void vq_prep(const float* __restrict__ cb,
                                               unsigned char* __restrict__ ws)
{
  _Float16* img = (_Float16*)ws;
  float* cn = (float*)(ws + 4u*1024u*1024u);

  const int tg   = blockIdx.x * 256 + threadIdx.x;  // 0..262143
  const int rg   = tg >> 4;                         // global code row 0..16383
  const int slot = tg & 15;
  const int m    = rg & (NCODE - 1);
  const int rowc = m & 63;
  const int srcslot = slot ^ (rowc & 7);

  const float* src = cb + (size_t)rg * DDIM + srcslot * 8;
  float4 a = *(const float4*)(src);
  float4 b = *(const float4*)(src + 4);
  float f[8] = {a.x, a.y, a.z, a.w, b.x, b.y, b.z, b.w};
  half8 hv;
  float nrm = 0.f;
#pragma unroll
  for (int j = 0; j < 8; ++j) {
    float v = f[j];
    nrm = fmaf(v, v, nrm);
    hv[j] = (_Float16)v;
  }
  size_t off = ((size_t)(rg >> 6) * 16384 + rowc * 256 + slot * 16) / 2; // halfs
  *(half8*)(img + off) = hv;
#pragma unroll
  for (int msk = 1; msk < 16; msk <<= 1) nrm += __shfl_xor(nrm, msk);
  if (slot == 0) cn[rg] = 0.5f * nrm;   // pre-fold the 0.5
}

// ---------------- kernel 2: main MFMA argmin + rescore + gather --------------
__global__ __launch_bounds__(256, 4) void vq_main(const float* __restrict__ x,
                                                  const float* __restrict__ cb,
                                                  const unsigned char* __restrict__ ws,
                                                  float* __restrict__ out)
{
  __shared__ __align__(16) unsigned char Ct[2][CHB]; // 32 KiB double buffer
  __shared__ int   fidx[BQ];
  __shared__ int   flaglist[BQ];
  __shared__ int   nflag;
  __shared__ float qrow[DDIM];
  __shared__ float redS[4];
  __shared__ int   redI[4];

  const int tid  = threadIdx.x;
  const int w    = tid >> 6, l = tid & 63;
  const int lrow = l & 15,  lg = l >> 4;
  const int h    = blockIdx.y;
  const int qbase = blockIdx.x * BQ;

  const unsigned char* img = ws;
  const float* cnh = (const float*)(ws + 4u*1024u*1024u) + h * NCODE;
  const float* cbh = cb + (size_t)h * NCODE * DDIM;

  if (tid == 0) nflag = 0;

  // ---- Q fragments (fp16) in registers: 32 queries per wave ----
  // A-frag lane map (16x16x32): row = lane&15, k = (lane>>4)*8 + j
  half8 Ah[2][4];
#pragma unroll
  for (int rf = 0; rf < 2; ++rf)
#pragma unroll
    for (int ks = 0; ks < 4; ++ks) {
      const float* p = x + (size_t)(qbase + w*32 + rf*16 + lrow) * 1024
                         + h * DDIM + ks * 32 + lg * 8;
      float4 a = *(const float4*)p;
      float4 b = *(const float4*)(p + 4);
      float f[8] = {a.x, a.y, a.z, a.w, b.x, b.y, b.z, b.w};
#pragma unroll
      for (int j = 0; j < 8; ++j) Ah[rf][ks][j] = (_Float16)f[j];
    }

  float best[8], sec[8];
  int   bidx[8];
#pragma unroll
  for (int i = 0; i < 8; ++i) { best[i] = 3.4e38f; sec[i] = 3.4e38f; bidx[i] = 0; }

  const size_t himgbase = (size_t)h * 32 * 16384;
  auto STAGE = [&](int buf, int c) {
    const unsigned char* g = img + himgbase + (size_t)c * 16384;
    unsigned char* lb = &Ct[buf][0];
#pragma unroll
    for (int r = 0; r < 4; ++r) {
      const int sub = (r * 4 + w) * 1024;  // wave-uniform LDS base
      __builtin_amdgcn_global_load_lds(
          (const __attribute__((address_space(1))) void*)(g + sub + l * 16),
          (__attribute__((address_space(3))) void*)(lb + sub), 16, 0, 0);
    }
  };

  STAGE(0, 0);
  __syncthreads();   // chunk 0 staged

  int cur = 0;
  for (int c = 0; c < NCHUNK; ++c) {
    if (c + 1 < NCHUNK) STAGE(cur ^ 1, c + 1);

    const int cbase = c * CCH;
    float cnv[4];
#pragma unroll
    for (int cf = 0; cf < 4; ++cf) cnv[cf] = cnh[cbase + cf * 16 + lrow];

    f32x4 acc[2][4];
#pragma unroll
    for (int rf = 0; rf < 2; ++rf)
#pragma unroll
      for (int cf = 0; cf < 4; ++cf) acc[rf][cf] = (f32x4){0.f, 0.f, 0.f, 0.f};

    const unsigned char* lb = &Ct[cur][0];
#pragma unroll
    for (int ks = 0; ks < 4; ++ks) {
#pragma unroll
      for (int cf = 0; cf < 4; ++cf) {
        // B-frag: col(code) = lane&15 -> LDS row cf*16+lrow; k = ks*32+lg*8
        const int row  = cf * 16 + lrow;
        const int boff = row * 256 + (((ks * 4 + lg) ^ (row & 7)) * 16);
        half8 bh = *(const half8*)(lb + boff);
#pragma unroll
        for (int rf = 0; rf < 2; ++rf)
          acc[rf][cf] = __builtin_amdgcn_mfma_f32_16x16x32_f16(Ah[rf][ks], bh, acc[rf][cf], 0, 0, 0);
      }
    }

    // score = 0.5*||c||^2 - q.c ; D-frag: col=lane&15, row=(lane>>4)*4+reg
#pragma unroll
    for (int cf = 0; cf < 4; ++cf) {
      const int m0 = cbase + cf * 16 + lrow;
#pragma unroll
      for (int rf = 0; rf < 2; ++rf)
#pragma unroll
        for (int r = 0; r < 4; ++r) {
          const float s = cnv[cf] - acc[rf][cf][r];
          const int sl = rf * 4 + r;
          if (s < best[sl]) { sec[sl] = best[sl]; best[sl] = s; bidx[sl] = m0; }
          else               sec[sl] = fminf(sec[sl], s);
        }
    }
    __syncthreads();   // all reads of buf done; next STAGE may overwrite
    cur ^= 1;
  }

  // ---- top-2 merge across the 16 lanes sharing lg (lane bits 0..3) ----
#pragma unroll
  for (int msk = 1; msk < 16; msk <<= 1) {
#pragma unroll
    for (int sl = 0; sl < 8; ++sl) {
      float ob = __shfl_xor(best[sl], msk);
      float os = __shfl_xor(sec[sl],  msk);
      int   oi = __shfl_xor(bidx[sl], msk);
      bool owin = (ob < best[sl]) || (ob == best[sl] && oi < bidx[sl]);
      float lose = owin ? best[sl] : ob;
      best[sl] = owin ? ob : best[sl];
      bidx[sl] = owin ? oi : bidx[sl];
      sec[sl]  = fminf(fminf(sec[sl], os), lose);
    }
  }
  if (lrow == 0) {
#pragma unroll
    for (int sl = 0; sl < 8; ++sl) {
      const int rf = sl >> 2, r = sl & 3;
      const int qloc = w * 32 + rf * 16 + lg * 4 + r;
      fidx[qloc] = bidx[sl];
      if (sec[sl] - best[sl] < TAU) {       // near-tie: exact rescore needed
        int p = atomicAdd(&nflag, 1);
        flaglist[p] = qloc;
      }
    }
  }
  __syncthreads();

  // ---- exact fp32 rescore of flagged queries (block-cooperative) ----
  const int nf = nflag;
  for (int fi = 0; fi < nf; ++fi) {
    const int qloc = flaglist[fi];
    if (tid < DDIM) qrow[tid] = x[(size_t)(qbase + qloc) * 1024 + h * DDIM + tid];
    __syncthreads();
    float bs = 3.4e38f; int bi = NCODE;
    for (int m = tid; m < NCODE; m += 256) {
      const float* cp = cbh + (size_t)m * DDIM;
      float dot = 0.f;
#pragma unroll
      for (int d = 0; d < DDIM; d += 4) {
        float4 c4 = *(const float4*)(cp + d);
        dot = fmaf(qrow[d + 0], c4.x, dot);
        dot = fmaf(qrow[d + 1], c4.y, dot);
        dot = fmaf(qrow[d + 2], c4.z, dot);
        dot = fmaf(qrow[d + 3], c4.w, dot);
      }
      const float s = cnh[m] - dot;
      if (s < bs) { bs = s; bi = m; }      // m increasing per thread
    }
#pragma unroll
    for (int msk = 1; msk < 64; msk <<= 1) {
      float ob = __shfl_xor(bs, msk);
      int   oi = __shfl_xor(bi, msk);
      if (ob < bs || (ob == bs && oi < bi)) { bs = ob; bi = oi; }
    }
    if (l == 0) { redS[w] = bs; redI[w] = bi; }
    __syncthreads();
    if (tid == 0) {
      float fb = redS[0]; int fbi = redI[0];
      for (int ww = 1; ww < 4; ++ww)
        if (redS[ww] < fb || (redS[ww] == fb && redI[ww] < fbi)) { fb = redS[ww]; fbi = redI[ww]; }
      fidx[qloc] = fbi;
    }
    __syncthreads();
  }

  // ---- gather winning codebook rows (coalesced 512B/row) ----
  const int half = tid >> 7, lane = tid & 127;
  for (int r = half; r < BQ; r += 2) {
    const int m = fidx[r];
    out[(size_t)(qbase + r) * 1024 + h * DDIM + lane] = cbh[(size_t)m * DDIM + lane];
  }
}

// ---------------- fallback (round-1 kernel, known-passing) -------------------
#define FBQ  128
#define FNCH 128
#define FDK  32
#define FLDP 132

__global__ __launch_bounds__(256) void vq_argmin_fallback(
    const float* __restrict__ x, const float* __restrict__ cb, float* __restrict__ out)
{
  __shared__ float Qs[FDK][FLDP];
  __shared__ float Cs[FDK][FLDP];
  __shared__ float cnc[FNCH];
  __shared__ float redS[FBQ][16];
  __shared__ int   redI[FBQ][16];
  __shared__ int   fidx[FBQ];

  const int h = blockIdx.y, qbase = blockIdx.x * FBQ, tid = threadIdx.x;
  const int ty = tid >> 4, tx = tid & 15;
  const float* xh  = x + (size_t)qbase * 1024 + (size_t)h * DDIM;
  const float* cbh = cb + (size_t)h * NCODE * DDIM;

  float best[8]; int bidx[8];
#pragma unroll
  for (int i = 0; i < 8; ++i) { best[i] = 3.4e38f; bidx[i] = 0; }
  float acc[8][8];
#pragma unroll
  for (int i = 0; i < 8; ++i)
#pragma unroll
    for (int j = 0; j < 8; ++j) acc[i][j] = 0.f;

  const int r0 = tid >> 3, c4 = tid & 7;
  for (int mc = 0; mc < NCODE / FNCH; ++mc) {
    for (int dk = 0; dk < DDIM / FDK; ++dk) {
      __syncthreads();
#pragma unroll
      for (int p = 0; p < 4; ++p) {
        const int q = p * 32 + r0;
        float4 v = *(const float4*)(xh + (size_t)q * 1024 + dk * FDK + c4 * 4);
        Qs[c4*4+0][q] = v.x; Qs[c4*4+1][q] = v.y; Qs[c4*4+2][q] = v.z; Qs[c4*4+3][q] = v.w;
        float4 wv = *(const float4*)(cbh + (size_t)(mc*FNCH + q) * DDIM + dk * FDK + c4 * 4);
        Cs[c4*4+0][q] = wv.x; Cs[c4*4+1][q] = wv.y; Cs[c4*4+2][q] = wv.z; Cs[c4*4+3][q] = wv.w;
      }
      __syncthreads();
#pragma unroll 8
      for (int d = 0; d < FDK; ++d) {
        float4 qa = *(const float4*)&Qs[d][ty*8];
        float4 qb = *(const float4*)&Qs[d][ty*8+4];
        float4 ca = *(const float4*)&Cs[d][tx*8];
        float4 cb4 = *(const float4*)&Cs[d][tx*8+4];
        const float qv[8] = {qa.x,qa.y,qa.z,qa.w,qb.x,qb.y,qb.z,qb.w};
        const float cv[8] = {ca.x,ca.y,ca.z,ca.w,cb4.x,cb4.y,cb4.z,cb4.w};
#pragma unroll
        for (int i = 0; i < 8; ++i)
#pragma unroll
          for (int j = 0; j < 8; ++j) acc[i][j] = fmaf(qv[i], cv[j], acc[i][j]);
      }
      if (tid < FNCH) {
        float s = 0.f;
#pragma unroll
        for (int d = 0; d < FDK; ++d) { float v = Cs[d][tid]; s = fmaf(v, v, s); }
        if (dk == 0) cnc[tid] = s; else cnc[tid] += s;
      }
    }
    __syncthreads();
#pragma unroll
    for (int j = 0; j < 8; ++j) {
      const int ml = tx * 8 + j;
      const float cn = 0.5f * cnc[ml];
      const int mg = mc * FNCH + ml;
#pragma unroll
      for (int i = 0; i < 8; ++i) {
        const float s = cn - acc[i][j];
        if (s < best[i]) { best[i] = s; bidx[i] = mg; }
        acc[i][j] = 0.f;
      }
    }
  }
#pragma unroll
  for (int i = 0; i < 8; ++i) { redS[ty*8+i][tx] = best[i]; redI[ty*8+i][tx] = bidx[i]; }
  __syncthreads();
  if (tid < FBQ) {
    float bs = redS[tid][0]; int bi = redI[tid][0];
#pragma unroll
    for (int t = 1; t < 16; ++t) {
      const float s = redS[tid][t]; const int ii = redI[tid][t];
      if (s < bs || (s == bs && ii < bi)) { bs = s; bi = ii; }
    }
    fidx[tid] = bi;
  }
  __syncthreads();
  const int half = tid >> 7, lane = tid & 127;
  for (int r = half; r < FBQ; r += 2) {
    const int m = fidx[r];
    out[(size_t)(qbase + r) * 1024 + (size_t)h * DDIM + lane] = cbh[(size_t)m * DDIM + lane];
  }
}

extern "C" void kernel_launch(void* const* d_in, const int* in_sizes, int n_in,
                              void* d_out, int out_size, void* d_ws, size_t ws_size,
                              hipStream_t stream)
{
  const float* x   = (const float*)d_in[0];
  const float* cbk = (const float*)d_in[1];
  float*       out = (float*)d_out;

  if (ws_size >= (size_t)WS_NEED) {
    vq_prep<<<dim3(1024), dim3(256), 0, stream>>>(cbk, (unsigned char*)d_ws);
    vq_main<<<dim3(NQTOT / BQ, NHEAD), dim3(256), 0, stream>>>(
        x, cbk, (const unsigned char*)d_ws, out);
  } else {
    vq_argmin_fallback<<<dim3(NQTOT / FBQ, NHEAD), dim3(256), 0, stream>>>(x, cbk, out);
  }
}

// Round 8
// 612.620 us; speedup vs baseline: 2.9913x; 2.9913x over previous
//
#include <hip/hip_runtime.h>
#include <stddef.h>
#include <stdint.h>

// VQ argmin + gather, MI355X.
//   x:         (8, 2048, 1024) fp32 -> 16384 query rows, head h uses cols [h*128,(h+1)*128)
//   codebooks: (8, 2048, 128)  fp32
//   out[q, h*128+d] = codebooks[h, argmin_m ||q-c||^2, d]
//
// Round 8 == round 5 resubmitted (rounds 5-7 were infra failures; this
// kernel has never actually run): round-3 validated structure (LDS-staged
// swizzled image, per-chunk double buffer, top-2 + exact-rescore) with:
//   1. no __launch_bounds__ min-waves (round-3 spill cause)
//   2. A-side fp16 hi/lo 2-pass vs single fp16(c) image: dot error is
//      c-rounding only, sigma ~0.003 (was 0.0045 1-pass)
//   3. TAU = 0.05 (round-2-validated margin; ~15 sigma here)

#define NHEAD  8
#define NCODE  2048
#define DDIM   128
#define NQTOT  16384
#define BQ     128            // queries per main block (4 waves x 32)
#define CCH    64             // codes per chunk
#define NCHUNK (NCODE / CCH)  // 32
#define CHB    (CCH * DDIM * 2) // 16384 B per chunk image
#define TAU    0.05f
#define WS_NEED (4u*1024u*1024u + 64u*1024u)

typedef __attribute__((ext_vector_type(8))) _Float16 half8;
typedef __attribute__((ext_vector_type(4))) float f32x4;

// ---------------- kernel 1: fp16 pre-swizzled codebook image + norms --------
// img layout: per (head,chunk) a 16 KiB block; within block:
//   row = code within chunk (0..63), 16 slots of 16B (8 fp16) per row
//   slot s holds elements of source slot (s ^ (row&7))
// reader at byte addr row*256 + ((kslot ^ (row&7))*16) sees k-elements kslot*8..+7.
__global__ __launch_bounds__(256) void vq_prep(const float* __restrict__ cb,
                                               unsigned char* __restrict__ ws)
{
  _Float16* img = (_Float16*)ws;
  float* cn = (float*)(ws + 4u*1024u*1024u);

  const int tg   = blockIdx.x * 256 + threadIdx.x;  // 0..262143
  const int rg   = tg >> 4;                         // global code row 0..16383
  const int slot = tg & 15;
  const int m    = rg & (NCODE - 1);
  const int rowc = m & 63;
  const int srcslot = slot ^ (rowc & 7);

  const float* src = cb + (size_t)rg * DDIM + srcslot * 8;
  float4 a = *(const float4*)(src);
  float4 b = *(const float4*)(src + 4);
  float f[8] = {a.x, a.y, a.z, a.w, b.x, b.y, b.z, b.w};
  half8 hv;
  float nrm = 0.f;
#pragma unroll
  for (int j = 0; j < 8; ++j) {
    float v = f[j];
    nrm = fmaf(v, v, nrm);
    hv[j] = (_Float16)v;
  }
  size_t off = ((size_t)(rg >> 6) * 16384 + rowc * 256 + slot * 16) / 2; // halfs
  *(half8*)(img + off) = hv;
#pragma unroll
  for (int msk = 1; msk < 16; msk <<= 1) nrm += __shfl_xor(nrm, msk);
  if (slot == 0) cn[rg] = 0.5f * nrm;   // pre-fold the 0.5
}

// ---------------- kernel 2: main MFMA argmin + rescore + gather --------------
__global__ __launch_bounds__(256) void vq_main(const float* __restrict__ x,
                                               const float* __restrict__ cb,
                                               const unsigned char* __restrict__ ws,
                                               float* __restrict__ out)
{
  __shared__ __align__(16) unsigned char Ct[2][CHB]; // 32 KiB double buffer
  __shared__ int   fidx[BQ];
  __shared__ int   flaglist[BQ];
  __shared__ int   nflag;
  __shared__ float qrow[DDIM];
  __shared__ float redS[4];
  __shared__ int   redI[4];

  const int tid  = threadIdx.x;
  const int w    = tid >> 6, l = tid & 63;
  const int lrow = l & 15,  lg = l >> 4;
  const int h    = blockIdx.y;
  const int qbase = blockIdx.x * BQ;

  const unsigned char* img = ws;
  const float* cnh = (const float*)(ws + 4u*1024u*1024u) + h * NCODE;
  const float* cbh = cb + (size_t)h * NCODE * DDIM;

  if (tid == 0) nflag = 0;

  // ---- Q fragments, fp16 hi + lo, in registers: 32 queries per wave ----
  // A-frag lane map (16x16x32): row = lane&15, k = (lane>>4)*8 + j
  half8 Ah[2][4], Al[2][4];
#pragma unroll
  for (int rf = 0; rf < 2; ++rf)
#pragma unroll
    for (int ks = 0; ks < 4; ++ks) {
      const float* p = x + (size_t)(qbase + w*32 + rf*16 + lrow) * 1024
                         + h * DDIM + ks * 32 + lg * 8;
      float4 a = *(const float4*)p;
      float4 b = *(const float4*)(p + 4);
      float f[8] = {a.x, a.y, a.z, a.w, b.x, b.y, b.z, b.w};
#pragma unroll
      for (int j = 0; j < 8; ++j) {
        _Float16 hh = (_Float16)f[j];
        Ah[rf][ks][j] = hh;
        Al[rf][ks][j] = (_Float16)(f[j] - (float)hh);
      }
    }

  float best[8], sec[8];
  int   bidx[8];
#pragma unroll
  for (int i = 0; i < 8; ++i) { best[i] = 3.4e38f; sec[i] = 3.4e38f; bidx[i] = 0; }

  const size_t himgbase = (size_t)h * 32 * 16384;
  auto STAGE = [&](int buf, int c) {
    const unsigned char* g = img + himgbase + (size_t)c * 16384;
    unsigned char* lb = &Ct[buf][0];
#pragma unroll
    for (int r = 0; r < 4; ++r) {
      const int sub = (r * 4 + w) * 1024;  // wave-uniform LDS base
      __builtin_amdgcn_global_load_lds(
          (const __attribute__((address_space(1))) void*)(g + sub + l * 16),
          (__attribute__((address_space(3))) void*)(lb + sub), 16, 0, 0);
    }
  };

  STAGE(0, 0);
  __syncthreads();   // chunk 0 staged

  int cur = 0;
  for (int c = 0; c < NCHUNK; ++c) {
    if (c + 1 < NCHUNK) STAGE(cur ^ 1, c + 1);

    const int cbase = c * CCH;
    float cnv[4];
#pragma unroll
    for (int cf = 0; cf < 4; ++cf) cnv[cf] = cnh[cbase + cf * 16 + lrow];

    f32x4 acc[2][4];
#pragma unroll
    for (int rf = 0; rf < 2; ++rf)
#pragma unroll
      for (int cf = 0; cf < 4; ++cf) acc[rf][cf] = (f32x4){0.f, 0.f, 0.f, 0.f};

    const unsigned char* lb = &Ct[cur][0];
#pragma unroll
    for (int ks = 0; ks < 4; ++ks) {
#pragma unroll
      for (int cf = 0; cf < 4; ++cf) {
        // B-frag: col(code) = lane&15 -> LDS row cf*16+lrow; k = ks*32+lg*8
        const int row  = cf * 16 + lrow;
        const int boff = row * 256 + (((ks * 4 + lg) ^ (row & 7)) * 16);
        half8 bh = *(const half8*)(lb + boff);
#pragma unroll
        for (int rf = 0; rf < 2; ++rf) {
          acc[rf][cf] = __builtin_amdgcn_mfma_f32_16x16x32_f16(Ah[rf][ks], bh, acc[rf][cf], 0, 0, 0);
          acc[rf][cf] = __builtin_amdgcn_mfma_f32_16x16x32_f16(Al[rf][ks], bh, acc[rf][cf], 0, 0, 0);
        }
      }
    }

    // score = 0.5*||c||^2 - q.c ; D-frag: col=lane&15, row=(lane>>4)*4+reg
#pragma unroll
    for (int cf = 0; cf < 4; ++cf) {
      const int m0 = cbase + cf * 16 + lrow;
#pragma unroll
      for (int rf = 0; rf < 2; ++rf)
#pragma unroll
        for (int r = 0; r < 4; ++r) {
          const float s = cnv[cf] - acc[rf][cf][r];
          const int sl = rf * 4 + r;
          if (s < best[sl]) { sec[sl] = best[sl]; best[sl] = s; bidx[sl] = m0; }
          else               sec[sl] = fminf(sec[sl], s);
        }
    }
    __syncthreads();   // all reads of buf done; next STAGE may overwrite
    cur ^= 1;
  }

  // ---- top-2 merge across the 16 lanes sharing lg (lane bits 0..3) ----
#pragma unroll
  for (int msk = 1; msk < 16; msk <<= 1) {
#pragma unroll
    for (int sl = 0; sl < 8; ++sl) {
      float ob = __shfl_xor(best[sl], msk);
      float os = __shfl_xor(sec[sl],  msk);
      int   oi = __shfl_xor(bidx[sl], msk);
      bool owin = (ob < best[sl]) || (ob == best[sl] && oi < bidx[sl]);
      float lose = owin ? best[sl] : ob;
      best[sl] = owin ? ob : best[sl];
      bidx[sl] = owin ? oi : bidx[sl];
      sec[sl]  = fminf(fminf(sec[sl], os), lose);
    }
  }
  if (lrow == 0) {
#pragma unroll
    for (int sl = 0; sl < 8; ++sl) {
      const int rf = sl >> 2, r = sl & 3;
      const int qloc = w * 32 + rf * 16 + lg * 4 + r;
      fidx[qloc] = bidx[sl];
      if (sec[sl] - best[sl] < TAU) {       // near-tie: exact rescore needed
        int p = atomicAdd(&nflag, 1);
        flaglist[p] = qloc;
      }
    }
  }
  __syncthreads();

  // ---- exact fp32 rescore of flagged queries (block-cooperative) ----
  const int nf = nflag;
  for (int fi = 0; fi < nf; ++fi) {
    const int qloc = flaglist[fi];
    if (tid < DDIM) qrow[tid] = x[(size_t)(qbase + qloc) * 1024 + h * DDIM + tid];
    __syncthreads();
    float bs = 3.4e38f; int bi = NCODE;
    for (int m = tid; m < NCODE; m += 256) {
      const float* cp = cbh + (size_t)m * DDIM;
      float dot = 0.f;
#pragma unroll
      for (int d = 0; d < DDIM; d += 4) {
        float4 c4 = *(const float4*)(cp + d);
        dot = fmaf(qrow[d + 0], c4.x, dot);
        dot = fmaf(qrow[d + 1], c4.y, dot);
        dot = fmaf(qrow[d + 2], c4.z, dot);
        dot = fmaf(qrow[d + 3], c4.w, dot);
      }
      const float s = cnh[m] - dot;
      if (s < bs) { bs = s; bi = m; }      // m increasing per thread
    }
#pragma unroll
    for (int msk = 1; msk < 64; msk <<= 1) {
      float ob = __shfl_xor(bs, msk);
      int   oi = __shfl_xor(bi, msk);
      if (ob < bs || (ob == bs && oi < bi)) { bs = ob; bi = oi; }
    }
    if (l == 0) { redS[w] = bs; redI[w] = bi; }
    __syncthreads();
    if (tid == 0) {
      float fb = redS[0]; int fbi = redI[0];
      for (int ww = 1; ww < 4; ++ww)
        if (redS[ww] < fb || (redS[ww] == fb && redI[ww] < fbi)) { fb = redS[ww]; fbi = redI[ww]; }
      fidx[qloc] = fbi;
    }
    __syncthreads();
  }

  // ---- gather winning codebook rows (coalesced 512B/row) ----
  const int half = tid >> 7, lane = tid & 127;
  for (int r = half; r < BQ; r += 2) {
    const int m = fidx[r];
    out[(size_t)(qbase + r) * 1024 + h * DDIM + lane] = cbh[(size_t)m * DDIM + lane];
  }
}

// ---------------- fallback (round-1 kernel, known-passing) -------------------
#define FBQ  128
#define FNCH 128
#define FDK  32
#define FLDP 132

__global__ __launch_bounds__(256) void vq_argmin_fallback(
    const float* __restrict__ x, const float* __restrict__ cb, float* __restrict__ out)
{
  __shared__ float Qs[FDK][FLDP];
  __shared__ float Cs[FDK][FLDP];
  __shared__ float cnc[FNCH];
  __shared__ float redS[FBQ][16];
  __shared__ int   redI[FBQ][16];
  __shared__ int   fidx[FBQ];

  const int h = blockIdx.y, qbase = blockIdx.x * FBQ, tid = threadIdx.x;
  const int ty = tid >> 4, tx = tid & 15;
  const float* xh  = x + (size_t)qbase * 1024 + (size_t)h * DDIM;
  const float* cbh = cb + (size_t)h * NCODE * DDIM;

  float best[8]; int bidx[8];
#pragma unroll
  for (int i = 0; i < 8; ++i) { best[i] = 3.4e38f; bidx[i] = 0; }
  float acc[8][8];
#pragma unroll
  for (int i = 0; i < 8; ++i)
#pragma unroll
    for (int j = 0; j < 8; ++j) acc[i][j] = 0.f;

  const int r0 = tid >> 3, c4 = tid & 7;
  for (int mc = 0; mc < NCODE / FNCH; ++mc) {
    for (int dk = 0; dk < DDIM / FDK; ++dk) {
      __syncthreads();
#pragma unroll
      for (int p = 0; p < 4; ++p) {
        const int q = p * 32 + r0;
        float4 v = *(const float4*)(xh + (size_t)q * 1024 + dk * FDK + c4 * 4);
        Qs[c4*4+0][q] = v.x; Qs[c4*4+1][q] = v.y; Qs[c4*4+2][q] = v.z; Qs[c4*4+3][q] = v.w;
        float4 wv = *(const float4*)(cbh + (size_t)(mc*FNCH + q) * DDIM + dk * FDK + c4 * 4);
        Cs[c4*4+0][q] = wv.x; Cs[c4*4+1][q] = wv.y; Cs[c4*4+2][q] = wv.z; Cs[c4*4+3][q] = wv.w;
      }
      __syncthreads();
#pragma unroll 8
      for (int d = 0; d < FDK; ++d) {
        float4 qa = *(const float4*)&Qs[d][ty*8];
        float4 qb = *(const float4*)&Qs[d][ty*8+4];
        float4 ca = *(const float4*)&Cs[d][tx*8];
        float4 cb4 = *(const float4*)&Cs[d][tx*8+4];
        const float qv[8] = {qa.x,qa.y,qa.z,qa.w,qb.x,qb.y,qb.z,qb.w};
        const float cv[8] = {ca.x,ca.y,ca.z,ca.w,cb4.x,cb4.y,cb4.z,cb4.w};
#pragma unroll
        for (int i = 0; i < 8; ++i)
#pragma unroll
          for (int j = 0; j < 8; ++j) acc[i][j] = fmaf(qv[i], cv[j], acc[i][j]);
      }
      if (tid < FNCH) {
        float s = 0.f;
#pragma unroll
        for (int d = 0; d < FDK; ++d) { float v = Cs[d][tid]; s = fmaf(v, v, s); }
        if (dk == 0) cnc[tid] = s; else cnc[tid] += s;
      }
    }
    __syncthreads();
#pragma unroll
    for (int j = 0; j < 8; ++j) {
      const int ml = tx * 8 + j;
      const float cn = 0.5f * cnc[ml];
      const int mg = mc * FNCH + ml;
#pragma unroll
      for (int i = 0; i < 8; ++i) {
        const float s = cn - acc[i][j];
        if (s < best[i]) { best[i] = s; bidx[i] = mg; }
        acc[i][j] = 0.f;
      }
    }
  }
#pragma unroll
  for (int i = 0; i < 8; ++i) { redS[ty*8+i][tx] = best[i]; redI[ty*8+i][tx] = bidx[i]; }
  __syncthreads();
  if (tid < FBQ) {
    float bs = redS[tid][0]; int bi = redI[tid][0];
#pragma unroll
    for (int t = 1; t < 16; ++t) {
      const float s = redS[tid][t]; const int ii = redI[tid][t];
      if (s < bs || (s == bs && ii < bi)) { bs = s; bi = ii; }
    }
    fidx[tid] = bi;
  }
  __syncthreads();
  const int half = tid >> 7, lane = tid & 127;
  for (int r = half; r < FBQ; r += 2) {
    const int m = fidx[r];
    out[(size_t)(qbase + r) * 1024 + (size_t)h * DDIM + lane] = cbh[(size_t)m * DDIM + lane];
  }
}

extern "C" void kernel_launch(void* const* d_in, const int* in_sizes, int n_in,
                              void* d_out, int out_size, void* d_ws, size_t ws_size,
                              hipStream_t stream)
{
  const float* x   = (const float*)d_in[0];
  const float* cbk = (const float*)d_in[1];
  float*       out = (float*)d_out;

  if (ws_size >= (size_t)WS_NEED) {
    vq_prep<<<dim3(1024), dim3(256), 0, stream>>>(cbk, (unsigned char*)d_ws);
    vq_main<<<dim3(NQTOT / BQ, NHEAD), dim3(256), 0, stream>>>(
        x, cbk, (const unsigned char*)d_ws, out);
  } else {
    vq_argmin_fallback<<<dim3(NQTOT / FBQ, NHEAD), dim3(256), 0, stream>>>(x, cbk, out);
  }
}